// Round 1
// baseline (5801.755 us; speedup 1.0000x reference)
//
#include <hip/hip_runtime.h>
#include <hip/hip_bf16.h>

// Sizes fixed by the problem
#define B_   2048
#define V_   1024
#define H_   512
#define E_   256
#define L_   32

typedef __attribute__((ext_vector_type(8))) short bf16x8;
typedef __attribute__((ext_vector_type(4))) float f32x4;
typedef unsigned short u16;
typedef unsigned int   u32;

__device__ __forceinline__ u16 f2bf(float x) {
    union { float f; u32 u; } v; v.f = x;
    u32 r = v.u + 0x7fffu + ((v.u >> 16) & 1u);   // RNE
    return (u16)(r >> 16);
}
__device__ __forceinline__ float sig_(float x)  { return 1.f / (1.f + __expf(-x)); }
__device__ __forceinline__ float tanh_(float x) { return 1.f - 2.f / (__expf(2.f * x) + 1.f); }

// -------------------------------------------------------------------------
// Preprocess: repack weights (fp32) into bf16 MFMA-fragment-major layouts.
// Fragment layout for mfma_f32_16x16x32_bf16 B-operand:
//   value(frag, lane l, elem e) = W[k][n], k = kstep*32 + (l>>4)*8 + e,
//                                          n = nfrag*16 + (l&15)
// so a wave's 64 lanes x 16B = 1KB contiguous per fragment (coalesced).
// w1f : [24 kstep][128 nfrag][64][8]  (K=768 = [e|h], N=2048 gates, n=g*512+j)
// wof : [16 kstep][ 64 vfrag][64][8]  (K=512 hidden, N=1024 vocab)
// wef : [32 kstep][ 16 efrag][64][8]  (K=1024 vocab, N=256 embed)
// b1  : b_ih + b_hh
// -------------------------------------------------------------------------
__global__ void prep(const float* __restrict__ W_ih, const float* __restrict__ W_hh,
                     const float* __restrict__ b_ih, const float* __restrict__ b_hh,
                     const float* __restrict__ W_out, const float* __restrict__ W_emb,
                     u16* __restrict__ w1f, u16* __restrict__ wof, u16* __restrict__ wef,
                     float* __restrict__ b1)
{
    int idx = blockIdx.x * 256 + threadIdx.x;
    if (idx < 1572864) {                       // W1 = [W_ih | W_hh], gates
        int e = idx & 7, lt = (idx >> 3) & 63, nf = (idx >> 9) & 127, ks = idx >> 16;
        int k = ks * 32 + ((lt >> 4) << 3) + e;
        int n = (nf << 4) + (lt & 15);         // n = g*512 + j (natural)
        float v = (k < E_) ? W_ih[n * E_ + k] : W_hh[n * H_ + (k - E_)];
        w1f[idx] = f2bf(v);
    } else if (idx < 2097152) {                // W_out
        int j = idx - 1572864;
        int e = j & 7, lt = (j >> 3) & 63, vf = (j >> 9) & 63, ks = j >> 15;
        int k = ks * 32 + ((lt >> 4) << 3) + e;
        int v = (vf << 4) + (lt & 15);
        wof[j] = f2bf(W_out[v * H_ + k]);
    } else if (idx < 2359296) {                // W_emb
        int j = idx - 2097152;
        int e = j & 7, lt = (j >> 3) & 63, ef = (j >> 9) & 15, ks = j >> 13;
        int k = ks * 32 + ((lt >> 4) << 3) + e;
        int c = (ef << 4) + (lt & 15);
        wef[j] = f2bf(W_emb[c * V_ + k]);
    } else if (idx < 2361344) {                // fused bias
        int j = idx - 2359296;
        b1[j] = b_ih[j] + b_hh[j];
    }
}

// -------------------------------------------------------------------------
// Persistent fused kernel. 128 blocks x 512 threads (8 waves). Block owns 16
// batch rows end-to-end over all 32 steps; no inter-block communication.
//  phase A: gates[16,2048] = ae[16,768] @ W1^T ; LSTM pointwise; h -> LDS
//  phase B: logits[16,1024] = h @ W_out^T ; E=exp(logit+g) ; rowsum; out
//  phase C: e[16,256] = E @ W_emb^T * invsum + b_emb -> LDS
// c state lives in VGPRs (lane<->(b,j) map is fixed across steps).
// Gate strips: wave w covers j in [64w,64w+64); the 4 gate fragments for a
// given j live in the SAME lane & register slot (acc[g][jj][r]).
// -------------------------------------------------------------------------
__global__ __launch_bounds__(512, 2)
void lstm_fused(const float* __restrict__ x, const float* __restrict__ gum,
                const u16* __restrict__ w1f, const u16* __restrict__ wof,
                const u16* __restrict__ wef, const float* __restrict__ b1,
                const float* __restrict__ b_out, const float* __restrict__ b_emb,
                const float* __restrict__ sos, float* __restrict__ out)
{
    __shared__ u16  ae[16][776];    // [b][0:256 e | 256:768 h], +8 pad (bank-spread)
    __shared__ u16  xs[16][1032];   // unnormalized exp(logits) in bf16, +8 pad
    __shared__ float red[16][8];    // per-wave row sums

    const int tid = threadIdx.x;
    const int w   = tid >> 6;       // wave 0..7
    const int l   = tid & 63;
    const int q   = l >> 4;         // quarter-wave
    const int col = l & 15;
    const int r0  = blockIdx.x << 4;

    // EOS row: out[b][32][v] = (v==0)
    for (int i = tid; i < 16 * V_; i += 512) {
        int b = i >> 10, v = i & (V_ - 1);
        out[((long)(r0 + b) * 33 + 32) * V_ + v] = (v == 0) ? 1.f : 0.f;
    }
    // e0 = sos, h0 = x
    for (int i = tid; i < 16 * E_; i += 512) {
        int b = i >> 8, k = i & (E_ - 1);
        ae[b][k] = f2bf(sos[k]);
    }
    for (int i = tid; i < 16 * H_; i += 512) {
        int b = i >> 9, k = i & (H_ - 1);
        ae[b][E_ + k] = f2bf(x[(r0 + b) * H_ + k]);
    }
    float creg[4][4];               // c state: [jj][r], j=64w+16jj+col, b=4q+r
    #pragma unroll
    for (int jj = 0; jj < 4; ++jj)
        #pragma unroll
        for (int r = 0; r < 4; ++r) creg[jj][r] = 0.f;

    __syncthreads();

    const f32x4 fz = {0.f, 0.f, 0.f, 0.f};

    for (int t = 0; t < L_; ++t) {
        // ---------------- phase A: gates ----------------
        f32x4 acc[4][4];
        #pragma unroll
        for (int g = 0; g < 4; ++g)
            #pragma unroll
            for (int jj = 0; jj < 4; ++jj) acc[g][jj] = fz;

        for (int ks = 0; ks < 24; ++ks) {
            bf16x8 af = *(const bf16x8*)&ae[col][ks * 32 + q * 8];
            #pragma unroll
            for (int g = 0; g < 4; ++g)
                #pragma unroll
                for (int jj = 0; jj < 4; ++jj) {
                    int nf = (g << 5) + (w << 2) + jj;       // n = g*512 + w*64 + jj*16
                    bf16x8 bfr = *(const bf16x8*)&w1f[((((ks << 7) + nf) << 6) | l) << 3];
                    acc[g][jj] = __builtin_amdgcn_mfma_f32_16x16x32_bf16(af, bfr, acc[g][jj], 0, 0, 0);
                }
        }
        __syncthreads();            // everyone done reading ae before h writes
        #pragma unroll
        for (int jj = 0; jj < 4; ++jj) {
            int j = (w << 6) + (jj << 4) + col;
            float bi = b1[j], bff = b1[H_ + j], bg = b1[2 * H_ + j], bo = b1[3 * H_ + j];
            #pragma unroll
            for (int r = 0; r < 4; ++r) {
                float gi = sig_(acc[0][jj][r] + bi);
                float gf = sig_(acc[1][jj][r] + bff);
                float gg = tanh_(acc[2][jj][r] + bg);
                float go = sig_(acc[3][jj][r] + bo);
                float c  = gf * creg[jj][r] + gi * gg;
                creg[jj][r] = c;
                float h  = go * tanh_(c);
                ae[(q << 2) + r][E_ + j] = f2bf(h);
            }
        }
        __syncthreads();            // h complete before phase B reads it

        // ---------------- phase B: logits + softmax ----------------
        f32x4 accB[8];
        #pragma unroll
        for (int f = 0; f < 8; ++f) accB[f] = fz;

        for (int ks = 0; ks < 16; ++ks) {
            bf16x8 af = *(const bf16x8*)&ae[col][E_ + ks * 32 + q * 8];
            #pragma unroll
            for (int f = 0; f < 8; ++f) {
                int vf = (w << 3) + f;
                bf16x8 bfr = *(const bf16x8*)&wof[((((ks << 6) + vf) << 6) | l) << 3];
                accB[f] = __builtin_amdgcn_mfma_f32_16x16x32_bf16(af, bfr, accB[f], 0, 0, 0);
            }
        }
        float eb[8][4];
        float ps[4] = {0.f, 0.f, 0.f, 0.f};
        const float* gt = gum + (long)t * B_ * V_ + (long)r0 * V_;
        #pragma unroll
        for (int f = 0; f < 8; ++f) {
            int v = (((w << 3) + f) << 4) | col;
            float bo = b_out[v];
            #pragma unroll
            for (int r = 0; r < 4; ++r) {
                int b = (q << 2) + r;
                // no max-subtraction: logits+gumbel <= ~20 -> exp safe in fp32
                float Ee = __expf(accB[f][r] + bo + gt[b * V_ + v]);
                eb[f][r] = Ee;
                ps[r] += Ee;
            }
        }
        #pragma unroll
        for (int m = 1; m < 16; m <<= 1)
            #pragma unroll
            for (int r = 0; r < 4; ++r) ps[r] += __shfl_xor(ps[r], m, 64);
        if (col == 0) {
            #pragma unroll
            for (int r = 0; r < 4; ++r) red[(q << 2) + r][w] = ps[r];
        }
        #pragma unroll
        for (int f = 0; f < 8; ++f) {          // stage unnormalized exp as bf16
            int v = (((w << 3) + f) << 4) | col;
            #pragma unroll
            for (int r = 0; r < 4; ++r) xs[(q << 2) + r][v] = f2bf(eb[f][r]);
        }
        __syncthreads();            // red + xs visible to all
        float invs[4];
        #pragma unroll
        for (int r = 0; r < 4; ++r) {
            float s = 0.f;
            #pragma unroll
            for (int ww = 0; ww < 8; ++ww) s += red[(q << 2) + r][ww];
            invs[r] = 1.f / s;
        }
        #pragma unroll
        for (int f = 0; f < 8; ++f) {          // write normalized softmax (fp32)
            int v = (((w << 3) + f) << 4) | col;
            #pragma unroll
            for (int r = 0; r < 4; ++r) {
                int b = (q << 2) + r;
                out[((long)(r0 + b) * 33 + t) * V_ + v] = eb[f][r] * invs[r];
            }
        }

        // ---------------- phase C: e_new ----------------
        f32x4 accC[2];
        #pragma unroll
        for (int f = 0; f < 2; ++f) accC[f] = fz;

        for (int ks = 0; ks < 32; ++ks) {
            bf16x8 af = *(const bf16x8*)&xs[col][ks * 32 + q * 8];
            #pragma unroll
            for (int f = 0; f < 2; ++f) {
                int ef = (w << 1) + f;
                bf16x8 bfr = *(const bf16x8*)&wef[((((ks << 4) + ef) << 6) | l) << 3];
                accC[f] = __builtin_amdgcn_mfma_f32_16x16x32_bf16(af, bfr, accC[f], 0, 0, 0);
            }
        }
        // e_new = (E @ W_emb^T) * invsum + b_emb   (linearity of the GEMM)
        #pragma unroll
        for (int f = 0; f < 2; ++f) {
            int ce = (((w << 1) + f) << 4) | col;
            float be = b_emb[ce];
            #pragma unroll
            for (int r = 0; r < 4; ++r)
                ae[(q << 2) + r][ce] = f2bf(accC[f][r] * invs[r] + be);
        }
        __syncthreads();            // e complete before next step's phase A
    }
}

extern "C" void kernel_launch(void* const* d_in, const int* in_sizes, int n_in,
                              void* d_out, int out_size, void* d_ws, size_t ws_size,
                              hipStream_t stream) {
    const float* x     = (const float*)d_in[0];
    const float* gum   = (const float*)d_in[1];
    const float* W_ih  = (const float*)d_in[2];
    const float* W_hh  = (const float*)d_in[3];
    const float* b_ih  = (const float*)d_in[4];
    const float* b_hh  = (const float*)d_in[5];
    const float* W_out = (const float*)d_in[6];
    const float* b_out = (const float*)d_in[7];
    const float* W_emb = (const float*)d_in[8];
    const float* b_emb = (const float*)d_in[9];
    const float* sos   = (const float*)d_in[10];
    float* out = (float*)d_out;

    // workspace layout (needs ~4.73 MB): bf16 fragment weights + fused bias
    char* ws = (char*)d_ws;
    u16*  w1f = (u16*)(ws);                    // 3,145,728 B
    u16*  wof = (u16*)(ws + 3145728);          // 1,048,576 B
    u16*  wef = (u16*)(ws + 4194304);          //   524,288 B
    float* b1 = (float*)(ws + 4718592);        //     8,192 B

    prep<<<9224, 256, 0, stream>>>(W_ih, W_hh, b_ih, b_hh, W_out, W_emb,
                                   w1f, wof, wef, b1);
    lstm_fused<<<128, 512, 0, stream>>>(x, gum, w1f, wof, wef, b1,
                                        b_out, b_emb, sos, out);
}